// Round 18
// baseline (112.541 us; speedup 1.0000x reference)
//
#include <hip/hip_runtime.h>
#include <hip/hip_cooperative_groups.h>

namespace cg = cooperative_groups;

typedef unsigned short u16;
typedef __attribute__((ext_vector_type(8))) short bf16x8;  // 8 bf16 = 16 B
typedef __attribute__((ext_vector_type(4))) float f32x4;

constexpr int   kN    = 8192;
constexpr int   kD    = 256;
constexpr float kInvD = 1.0f / 256.0f;
constexpr float kInv2D = 2.0f / 256.0f;   // 2/D
constexpr float kInvN = 1.0f / 8192.0f;

#define GLOAD_LDS16(gptr, ldsptr)                                                   \
  __builtin_amdgcn_global_load_lds(                                                 \
      (const __attribute__((address_space(1))) unsigned int*)(gptr),                \
      (__attribute__((address_space(3))) unsigned int*)(ldsptr), 16, 0, 0)

__device__ __forceinline__ u16 f2bf(float f) {
  union { float f; unsigned u; } c; c.f = f;
  unsigned r = c.u + 0x7fffu + ((c.u >> 16) & 1u);
  return (u16)(r >> 16);
}

// ===========================================================================
// Shared tile machinery (R10's proven body — single 32 KB buffer pair).
// ===========================================================================
#define STAGE_BOTH(Ad, Bd, ia0, jb0, kt)                                      \
  {                                                                           \
    _Pragma("unroll")                                                         \
    for (int cc = 0; cc < 4; ++cc) {                                          \
      const int rr  = cc * 32 + sr;                                           \
      const int ksl = sl ^ (rr & 7);                                          \
      const u16* ga = bf + (size_t)((ia0) + rr) * kD + (kt) * 64 + ksl * 8;   \
      const u16* gb = bf + (size_t)((jb0) + rr) * kD + (kt) * 64 + ksl * 8;   \
      GLOAD_LDS16(ga, (Ad) + rr * 64 + sl * 8);                               \
      GLOAD_LDS16(gb, (Bd) + rr * 64 + sl * 8);                               \
    }                                                                         \
  }

#define COMPUTE_SLAB(Asrc, Bsrc)                                              \
  {                                                                           \
    _Pragma("unroll")                                                         \
    for (int k32 = 0; k32 < 2; ++k32) {                                       \
      bf16x8 a[4], bv[4];                                                     \
      _Pragma("unroll")                                                       \
      for (int mi = 0; mi < 4; ++mi) {                                        \
        const int ra   = wm * 64 + mi * 16 + llo;                             \
        const int slot = (k32 * 4 + lhi) ^ (ra & 7);                          \
        a[mi] = *(const bf16x8*)((Asrc) + ra * 64 + slot * 8);                \
      }                                                                       \
      _Pragma("unroll")                                                       \
      for (int ni = 0; ni < 4; ++ni) {                                        \
        const int rb   = wn * 64 + ni * 16 + llo;                             \
        const int slot = (k32 * 4 + lhi) ^ (rb & 7);                          \
        bv[ni] = *(const bf16x8*)((Bsrc) + rb * 64 + slot * 8);               \
      }                                                                       \
      __builtin_amdgcn_s_setprio(1);                                          \
      _Pragma("unroll")                                                       \
      for (int mi = 0; mi < 4; ++mi)                                          \
        _Pragma("unroll")                                                     \
        for (int ni = 0; ni < 4; ++ni)                                        \
          acc[mi][ni] = __builtin_amdgcn_mfma_f32_16x16x32_bf16(              \
              a[mi], bv[ni], acc[mi][ni], 0, 0, 0);                           \
      __builtin_amdgcn_s_setprio(0);                                          \
    }                                                                         \
  }

// epilogue for one tile: accumulate rowacc, col atomics if docol
#define TILE_EPILOGUE(ia0, jb0, docol)                                        \
  {                                                                           \
    float sqjm1[4], idj[4];                                                   \
    _Pragma("unroll")                                                         \
    for (int ni = 0; ni < 4; ++ni) {                                          \
      const float2 p = sqid[(jb0) + wn * 64 + ni * 16 + llo];                 \
      sqjm1[ni] = p.x * kInvD - 1.0f;                                         \
      idj[ni]   = p.y;                                                        \
    }                                                                         \
    float colacc[4] = {};                                                     \
    _Pragma("unroll")                                                         \
    for (int mi = 0; mi < 4; ++mi)                                            \
      _Pragma("unroll")                                                       \
      for (int ni = 0; ni < 4; ++ni)                                          \
        _Pragma("unroll")                                                     \
        for (int rr = 0; rr < 4; ++rr) {                                      \
          float s1 = fmaf(acc[mi][ni][rr], -kInv2D, sqi_s[mi][rr] + sqjm1[ni]); \
          s1 += (idi[mi][rr] == idj[ni]) ? 1.0f : 0.0f;                       \
          const float tt = s1 * s1;                                           \
          rowacc[mi][rr] += tt;                                               \
          colacc[ni] += tt;                                                   \
        }                                                                     \
    if (docol) {                                                              \
      _Pragma("unroll")                                                       \
      for (int ni = 0; ni < 4; ++ni) {                                        \
        float v = colacc[ni];                                                 \
        v += __shfl_xor(v, 16);                                               \
        v += __shfl_xor(v, 32);                                               \
        if (lhi == 0)                                                         \
          atomicAdd(&out[(jb0) + wn * 64 + ni * 16 + llo], v * kInvN);        \
      }                                                                       \
    }                                                                         \
  }

#define ROW_FLUSH(ia0)                                                        \
  {                                                                           \
    _Pragma("unroll")                                                         \
    for (int mi = 0; mi < 4; ++mi)                                            \
      _Pragma("unroll")                                                       \
      for (int rr = 0; rr < 4; ++rr) {                                        \
        float v = rowacc[mi][rr];                                             \
        v += __shfl_xor(v, 1);                                                \
        v += __shfl_xor(v, 2);                                                \
        v += __shfl_xor(v, 4);                                                \
        v += __shfl_xor(v, 8);                                                \
        if (llo == 0)                                                         \
          atomicAdd(&out[(ia0) + wm * 64 + mi * 16 + lhi * 4 + rr], v * kInvN); \
      }                                                                       \
  }

// ===========================================================================
// Path 1: ONE cooperative kernel (1 graph node). 32 KB LDS + ~120 VGPR
// gives 4-5 blocks/CU capacity >> 512-block co-residency requirement, so
// the cooperative occupancy check passes with 2x margin (R17's 64 KB LDS
// sat exactly at the boundary and the launch was refused -> out never
// written). Return code IS checked in kernel_launch; fallback below.
// ===========================================================================
__global__ __launch_bounds__(256, 2) void simloss_coop(
    const float* __restrict__ samples, const float* __restrict__ input1,
    u16* __restrict__ bf, float2* __restrict__ sqid, float* __restrict__ out)
{
  __shared__ u16 Abuf[8192];  // 16 KB
  __shared__ u16 Bbuf[8192];  // 16 KB

  const int bid  = blockIdx.x;     // 0..511
  const int tid  = threadIdx.x;
  const int lane = tid & 63;
  const int w    = tid >> 6;

  // ---- Phase A: prep (16 rows/block) ----
#pragma unroll
  for (int it = 0; it < 4; ++it) {
    const int row = bid * 16 + w * 4 + it;
    const float4 v = *(const float4*)(samples + (size_t)row * kD + lane * 4);
    *(ushort4*)(bf + (size_t)row * kD + lane * 4) =
        make_ushort4(f2bf(v.x), f2bf(v.y), f2bf(v.z), f2bf(v.w));
    float ss = v.x * v.x + v.y * v.y + v.z * v.z + v.w * v.w;
#pragma unroll
    for (int m = 32; m >= 1; m >>= 1) ss += __shfl_xor(ss, m);
    if (lane == 0) {
      sqid[row] = make_float2(ss, input1[row * 32 + 7]);  // input1[i,0,F-1]
      out[row]  = 0.0f;
    }
  }

  cg::this_grid().sync();

  // ---- Phase B: R10 triangle main (4 tiles, rolled, carried rowacc) ----
  const int wm  = w >> 1;
  const int wn  = w & 1;
  const int llo = lane & 15;
  const int lhi = lane >> 4;

  const int r  = bid & 63;
  const int h  = bid >> 6;
  const int i0 = r * 128;

  const int sr = tid >> 3;
  const int sl = tid & 7;

  float sqi_s[4][4], idi[4][4];
#pragma unroll
  for (int mi = 0; mi < 4; ++mi)
#pragma unroll
    for (int rr = 0; rr < 4; ++rr) {
      const float2 p = sqid[i0 + wm * 64 + mi * 16 + lhi * 4 + rr];
      sqi_s[mi][rr] = p.x * kInvD;
      idi[mi][rr]   = p.y;
    }

  float rowacc[4][4] = {};

  for (int t = 0; t < 4; ++t) {
    const int c  = h * 4 + t;
    const int j0 = ((r + c) & 63) * 128;

    f32x4 acc[4][4];
#pragma unroll
    for (int mi = 0; mi < 4; ++mi)
#pragma unroll
      for (int ni = 0; ni < 4; ++ni) acc[mi][ni] = {0.f, 0.f, 0.f, 0.f};

#pragma unroll
    for (int kt = 0; kt < 4; ++kt) {
      STAGE_BOTH(Abuf, Bbuf, i0, j0, kt);
      __syncthreads();
      COMPUTE_SLAB(Abuf, Bbuf);
      __syncthreads();
    }

    TILE_EPILOGUE(i0, j0, (c != 0));
  }
  ROW_FLUSH(i0);

  // ---- Phase C: distance-32 tiles on blocks 0..31 ----
  if (bid < 32) {
    const int di0 = bid * 128;
    const int dj0 = (bid + 32) * 128;

    f32x4 acc[4][4];
#pragma unroll
    for (int mi = 0; mi < 4; ++mi)
#pragma unroll
      for (int ni = 0; ni < 4; ++ni) acc[mi][ni] = {0.f, 0.f, 0.f, 0.f};

#pragma unroll
    for (int kt = 0; kt < 4; ++kt) {
      STAGE_BOTH(Abuf, Bbuf, di0, dj0, kt);
      __syncthreads();
      COMPUTE_SLAB(Abuf, Bbuf);
      __syncthreads();
    }

    float dsqi[4][4], didi[4][4];
#pragma unroll
    for (int mi = 0; mi < 4; ++mi)
#pragma unroll
      for (int rr = 0; rr < 4; ++rr) {
        const float2 p = sqid[di0 + wm * 64 + mi * 16 + lhi * 4 + rr];
        dsqi[mi][rr] = p.x * kInvD;
        didi[mi][rr] = p.y;
      }
    // reuse epilogue macro via aliased names
    {
      float (&sqi_s)[4][4] = dsqi;
      float (&idi)[4][4]   = didi;
      float drow[4][4] = {};
      float (&rowacc)[4][4] = drow;
      TILE_EPILOGUE(di0, dj0, true);
      ROW_FLUSH(di0);
    }
  }
}

// ===========================================================================
// Path 2 fallback (R14 exact, best measured passing: 44.8 us) — used when
// the cooperative launch is refused (occupancy or capture).
// ===========================================================================
__global__ __launch_bounds__(256) void prep_kernel(
    const float* __restrict__ samples, const float* __restrict__ input1,
    u16* __restrict__ bf, float2* __restrict__ sqid, float* __restrict__ out)
{
  const int row  = blockIdx.x * 4 + (threadIdx.x >> 6);
  const int lane = threadIdx.x & 63;
  const float4 v = *(const float4*)(samples + (size_t)row * kD + lane * 4);
  *(ushort4*)(bf + (size_t)row * kD + lane * 4) =
      make_ushort4(f2bf(v.x), f2bf(v.y), f2bf(v.z), f2bf(v.w));
  float ss = v.x * v.x + v.y * v.y + v.z * v.z + v.w * v.w;
#pragma unroll
  for (int m = 32; m >= 1; m >>= 1) ss += __shfl_xor(ss, m);
  if (lane == 0) {
    sqid[row] = make_float2(ss, input1[row * 32 + 7]);
    out[row]  = 0.0f;
  }
}

__global__ __launch_bounds__(256, 2) void simloss_main(
    const u16* __restrict__ bf, const float2* __restrict__ sqid,
    float* __restrict__ out)
{
  __shared__ u16 Abuf[8192];
  __shared__ u16 Bbuf[8192];

  const int tid  = threadIdx.x;
  const int lane = tid & 63;
  const int w    = tid >> 6;
  const int wm = w >> 1, wn = w & 1, llo = lane & 15, lhi = lane >> 4;

  const int r  = blockIdx.x;
  const int h  = blockIdx.y;
  const int i0 = r * 128;
  const int sr = tid >> 3, sl = tid & 7;

  float sqi_s[4][4], idi[4][4];
#pragma unroll
  for (int mi = 0; mi < 4; ++mi)
#pragma unroll
    for (int rr = 0; rr < 4; ++rr) {
      const float2 p = sqid[i0 + wm * 64 + mi * 16 + lhi * 4 + rr];
      sqi_s[mi][rr] = p.x * kInvD;
      idi[mi][rr]   = p.y;
    }

  float rowacc[4][4] = {};

  for (int t = 0; t < 4; ++t) {
    const int c  = h * 4 + t;
    const int j0 = ((r + c) & 63) * 128;

    f32x4 acc[4][4];
#pragma unroll
    for (int mi = 0; mi < 4; ++mi)
#pragma unroll
      for (int ni = 0; ni < 4; ++ni) acc[mi][ni] = {0.f, 0.f, 0.f, 0.f};

#pragma unroll
    for (int kt = 0; kt < 4; ++kt) {
      STAGE_BOTH(Abuf, Bbuf, i0, j0, kt);
      __syncthreads();
      COMPUTE_SLAB(Abuf, Bbuf);
      __syncthreads();
    }

    TILE_EPILOGUE(i0, j0, (c != 0));
  }
  ROW_FLUSH(i0);
}

__global__ __launch_bounds__(256, 2) void simloss_d32(
    const u16* __restrict__ bf, const float2* __restrict__ sqid,
    float* __restrict__ out)
{
  __shared__ u16 Abuf[8192];
  __shared__ u16 Bbuf[8192];

  const int tid  = threadIdx.x;
  const int lane = tid & 63;
  const int w    = tid >> 6;
  const int wm = w >> 1, wn = w & 1, llo = lane & 15, lhi = lane >> 4;

  const int i0 = blockIdx.x * 128;
  const int j0 = (blockIdx.x + 32) * 128;
  const int sr = tid >> 3, sl = tid & 7;

  float sqi_s[4][4], idi[4][4];
#pragma unroll
  for (int mi = 0; mi < 4; ++mi)
#pragma unroll
    for (int rr = 0; rr < 4; ++rr) {
      const float2 p = sqid[i0 + wm * 64 + mi * 16 + lhi * 4 + rr];
      sqi_s[mi][rr] = p.x * kInvD;
      idi[mi][rr]   = p.y;
    }

  float rowacc[4][4] = {};

  f32x4 acc[4][4];
#pragma unroll
  for (int mi = 0; mi < 4; ++mi)
#pragma unroll
    for (int ni = 0; ni < 4; ++ni) acc[mi][ni] = {0.f, 0.f, 0.f, 0.f};

#pragma unroll
  for (int kt = 0; kt < 4; ++kt) {
    STAGE_BOTH(Abuf, Bbuf, i0, j0, kt);
    __syncthreads();
    COMPUTE_SLAB(Abuf, Bbuf);
    __syncthreads();
  }

  TILE_EPILOGUE(i0, j0, true);
  ROW_FLUSH(i0);
}

// ---------------------------------------------------------------------------
extern "C" void kernel_launch(void* const* d_in, const int* in_sizes, int n_in,
                              void* d_out, int out_size, void* d_ws, size_t ws_size,
                              hipStream_t stream) {
  const float* samples = (const float*)d_in[0];
  const float* input1  = (const float*)d_in[1];
  float* out = (float*)d_out;

  char* ws = (char*)d_ws;
  u16*    bf   = (u16*)ws;                                  // 4 MB bf16 samples
  float2* sqid = (float2*)(ws + (size_t)4 * 1024 * 1024);   // 64 KB {sq, id}

  void* args[] = {(void*)&samples, (void*)&input1, (void*)&bf,
                  (void*)&sqid, (void*)&out};
  hipError_t e = hipLaunchCooperativeKernel((const void*)simloss_coop,
                                            dim3(512), dim3(256), args, 0, stream);
  if (e != hipSuccess) {
    // fallback: R14's proven 3-kernel path
    prep_kernel<<<kN / 4, 256, 0, stream>>>(samples, input1, bf, sqid, out);
    simloss_main<<<dim3(64, 8), 256, 0, stream>>>(bf, sqid, out);
    simloss_d32<<<32, 256, 0, stream>>>(bf, sqid, out);
  }
}

// Round 19
// 51.249 us; speedup vs baseline: 2.1959x; 2.1959x over previous
//
#include <hip/hip_runtime.h>

typedef unsigned short u16;
typedef __attribute__((ext_vector_type(8))) short bf16x8;  // 8 bf16 = 16 B
typedef __attribute__((ext_vector_type(4))) float f32x4;

constexpr int   kN    = 8192;
constexpr int   kD    = 256;
constexpr float kInvD = 1.0f / 256.0f;
constexpr float kInv2D = 2.0f / 256.0f;   // 2/D
constexpr float kInvN = 1.0f / 8192.0f;

#define GLOAD_LDS16(gptr, ldsptr)                                                   \
  __builtin_amdgcn_global_load_lds(                                                 \
      (const __attribute__((address_space(1))) unsigned int*)(gptr),                \
      (__attribute__((address_space(3))) unsigned int*)(ldsptr), 16, 0, 0)

__device__ __forceinline__ u16 f2bf(float f) {
  union { float f; unsigned u; } c; c.f = f;
  unsigned r = c.u + 0x7fffu + ((c.u >> 16) & 1u);
  return (u16)(r >> 16);
}

// ---------------------------------------------------------------------------
// K1 prep (R14 verbatim): bf16 convert, {sq,id}, out=0. One wave per row.
// ---------------------------------------------------------------------------
__global__ __launch_bounds__(256) void prep_kernel(
    const float* __restrict__ samples, const float* __restrict__ input1,
    u16* __restrict__ bf, float2* __restrict__ sqid, float* __restrict__ out)
{
  const int row  = blockIdx.x * 4 + (threadIdx.x >> 6);
  const int lane = threadIdx.x & 63;
  const float4 v = *(const float4*)(samples + (size_t)row * kD + lane * 4);
  *(ushort4*)(bf + (size_t)row * kD + lane * 4) =
      make_ushort4(f2bf(v.x), f2bf(v.y), f2bf(v.z), f2bf(v.w));
  float ss = v.x * v.x + v.y * v.y + v.z * v.z + v.w * v.w;
#pragma unroll
  for (int m = 32; m >= 1; m >>= 1) ss += __shfl_xor(ss, m);
  if (lane == 0) {
    sqid[row] = make_float2(ss, input1[row * 32 + 7]);  // input1[i,0,F-1]
    out[row]  = 0.0f;
  }
}

// ---------------------------------------------------------------------------
// K2 main: triangle strips with FULL-K PHASES.
//
// R14 post-mortem: per-K-step stall ~2600cy vs ~350cy compute; dbuf could
// not hide staging because compute-per-phase < load latency. Fix: phase =
// K=128 (compute ~1500cy LDS-BW-bound) > stage 32KB (~1000cy) -> the
// syncthreads vmcnt drain is cheap. A[128][256] staged ONCE per block
// (resident 64 KB); B half-tiles double-buffered 2 x 32 KB. 128 KB dynamic
// LDS -> 1 block/CU, grid = 256 blocks (64 strips x 4 chunks x 8 tiles) =
// exactly one generation, no tail. Tile loop: R1's proven healthy shape
// (plain rolled loop, compile-time trip 8, carried rowacc, hoisted i-side).
// Swizzle (rule #21): linear LDS dest, source col-slot ^= (row&7), read
// slot ^= (row&7). 32-slot A rows / 16-slot B rows -> 2-way max (free).
// Coverage: distances c = 8h+t in 0..31; d32 pairs in simloss_d32;
// d >= 33 reached as (strip b, c = 64-d).
// ---------------------------------------------------------------------------
__global__ __launch_bounds__(256, 1) void simloss_main(
    const u16* __restrict__ bf, const float2* __restrict__ sqid,
    float* __restrict__ out)
{
  extern __shared__ u16 smem[];
  u16* Alds = smem;            // [128][256] = 64 KB, resident
  u16* Bb0  = smem + 32768;    // [128][128] = 32 KB, half-tile dbuf
  u16* Bb1  = smem + 49152;    // [128][128] = 32 KB

  const int tid  = threadIdx.x;
  const int lane = tid & 63;
  const int w    = tid >> 6;
  const int wm = w >> 1, wn = w & 1, llo = lane & 15, lhi = lane >> 4;

  const int r  = blockIdx.x;   // strip 0..63
  const int h  = blockIdx.y;   // chunk 0..3 (8 offsets each)
  const int i0 = r * 128;

  // ---- one-time A staging: 64 KB, 16 iters x 256 threads x 16 B ----
#pragma unroll
  for (int it = 0; it < 16; ++it) {
    const int unit = it * 256 + tid;       // 4096 16B units
    const int row  = unit >> 5;            // 32 slots per 256-col row
    const int sl   = unit & 31;
    const int ksl  = sl ^ (row & 7);       // inverse-swizzled source
    GLOAD_LDS16(bf + (size_t)(i0 + row) * kD + ksl * 8,
                Alds + row * 256 + sl * 8);
  }

  // stage one B half-tile (32 KB): rows j0.., K-half kh
#define STAGE_BH(dst, jb0, kh)                                               \
  {                                                                          \
    _Pragma("unroll")                                                        \
    for (int it = 0; it < 8; ++it) {                                         \
      const int unit = it * 256 + tid;     /* 2048 16B units */              \
      const int row  = unit >> 4;          /* 16 slots per 128-col row */    \
      const int sl   = unit & 15;                                            \
      const int ksl  = sl ^ (row & 7);                                       \
      GLOAD_LDS16(bf + (size_t)((jb0) + row) * kD + (kh) * 128 + ksl * 8,    \
                  (dst) + row * 128 + sl * 8);                               \
    }                                                                        \
  }

  // compute one K=128 half: 4 k32 steps; A slots offset kh*16
#define COMPUTE_HALF(Bsrc, kh)                                               \
  {                                                                          \
    _Pragma("unroll")                                                        \
    for (int k32 = 0; k32 < 4; ++k32) {                                      \
      bf16x8 a[4], bv[4];                                                    \
      _Pragma("unroll")                                                      \
      for (int mi = 0; mi < 4; ++mi) {                                       \
        const int ra   = wm * 64 + mi * 16 + llo;                            \
        const int slot = ((kh) * 16 + k32 * 4 + lhi) ^ (ra & 7);             \
        a[mi] = *(const bf16x8*)(Alds + ra * 256 + slot * 8);                \
      }                                                                      \
      _Pragma("unroll")                                                      \
      for (int ni = 0; ni < 4; ++ni) {                                       \
        const int rb   = wn * 64 + ni * 16 + llo;                            \
        const int slot = (k32 * 4 + lhi) ^ (rb & 7);                         \
        bv[ni] = *(const bf16x8*)((Bsrc) + rb * 128 + slot * 8);             \
      }                                                                      \
      __builtin_amdgcn_s_setprio(1);                                         \
      _Pragma("unroll")                                                      \
      for (int mi = 0; mi < 4; ++mi)                                         \
        _Pragma("unroll")                                                    \
        for (int ni = 0; ni < 4; ++ni)                                       \
          acc[mi][ni] = __builtin_amdgcn_mfma_f32_16x16x32_bf16(             \
              a[mi], bv[ni], acc[mi][ni], 0, 0, 0);                          \
      __builtin_amdgcn_s_setprio(0);                                         \
    }                                                                        \
  }

  // i-side row data: block-constant, hoisted
  float sqi_s[4][4], idi[4][4];
#pragma unroll
  for (int mi = 0; mi < 4; ++mi)
#pragma unroll
    for (int rr = 0; rr < 4; ++rr) {
      const float2 p = sqid[i0 + wm * 64 + mi * 16 + lhi * 4 + rr];
      sqi_s[mi][rr] = p.x * kInvD;
      idi[mi][rr]   = p.y;
    }

  float rowacc[4][4] = {};  // carried across tiles

  // prologue: stage B0 <- (t=0, half 0); sync also covers A staging
  {
    const int j0p = ((r + h * 8) & 63) * 128;
    STAGE_BH(Bb0, j0p, 0);
  }
  __syncthreads();

  for (int t = 0; t < 8; ++t) {
    const int c   = h * 8 + t;                 // tile distance 0..31
    const int j0  = ((r + c) & 63) * 128;
    const int j0n = ((r + c + 1) & 63) * 128;  // next tile (last: harmless)

    f32x4 acc[4][4];
#pragma unroll
    for (int mi = 0; mi < 4; ++mi)
#pragma unroll
      for (int ni = 0; ni < 4; ++ni) acc[mi][ni] = {0.f, 0.f, 0.f, 0.f};

    // phase 0: stage half1 -> Bb1, compute half0 from Bb0
    STAGE_BH(Bb1, j0, 1);
    COMPUTE_HALF(Bb0, 0);
    __syncthreads();
    // phase 1: stage NEXT tile half0 -> Bb0, compute half1 from Bb1
    STAGE_BH(Bb0, j0n, 0);
    COMPUTE_HALF(Bb1, 1);
    __syncthreads();

    // ---- per-tile epilogue ----
    float sqjm1[4], idj[4];
#pragma unroll
    for (int ni = 0; ni < 4; ++ni) {
      const float2 p = sqid[j0 + wn * 64 + ni * 16 + llo];
      sqjm1[ni] = p.x * kInvD - 1.0f;
      idj[ni]   = p.y;
    }

    float colacc[4] = {};
#pragma unroll
    for (int mi = 0; mi < 4; ++mi)
#pragma unroll
      for (int ni = 0; ni < 4; ++ni)
#pragma unroll
        for (int rr = 0; rr < 4; ++rr) {
          float s1 = fmaf(acc[mi][ni][rr], -kInv2D, sqi_s[mi][rr] + sqjm1[ni]);
          s1 += (idi[mi][rr] == idj[ni]) ? 1.0f : 0.0f;
          const float tt = s1 * s1;
          rowacc[mi][rr] += tt;
          colacc[ni] += tt;
        }

    if (c != 0) {
#pragma unroll
      for (int ni = 0; ni < 4; ++ni) {
        float v = colacc[ni];
        v += __shfl_xor(v, 16);
        v += __shfl_xor(v, 32);
        if (lhi == 0)
          atomicAdd(&out[j0 + wn * 64 + ni * 16 + llo], v * kInvN);
      }
    }
  }

  // ---- block end: row sums ----
#pragma unroll
  for (int mi = 0; mi < 4; ++mi)
#pragma unroll
    for (int rr = 0; rr < 4; ++rr) {
      float v = rowacc[mi][rr];
      v += __shfl_xor(v, 1);
      v += __shfl_xor(v, 2);
      v += __shfl_xor(v, 4);
      v += __shfl_xor(v, 8);
      if (llo == 0)
        atomicAdd(&out[i0 + wm * 64 + mi * 16 + lhi * 4 + rr], v * kInvN);
    }
}

// ---------------------------------------------------------------------------
// K3 d32 (R14 verbatim): the 32 distance-32 tiles, 32 KB static LDS.
// ---------------------------------------------------------------------------
__global__ __launch_bounds__(256, 2) void simloss_d32(
    const u16* __restrict__ bf, const float2* __restrict__ sqid,
    float* __restrict__ out)
{
  __shared__ u16 Abuf[8192];
  __shared__ u16 Bbuf[8192];

  const int tid  = threadIdx.x;
  const int lane = tid & 63;
  const int w    = tid >> 6;
  const int wm = w >> 1, wn = w & 1, llo = lane & 15, lhi = lane >> 4;

  const int i0 = blockIdx.x * 128;
  const int j0 = (blockIdx.x + 32) * 128;
  const int sr = tid >> 3, sl = tid & 7;

  f32x4 acc[4][4];
#pragma unroll
  for (int mi = 0; mi < 4; ++mi)
#pragma unroll
    for (int ni = 0; ni < 4; ++ni) acc[mi][ni] = {0.f, 0.f, 0.f, 0.f};

#pragma unroll
  for (int kt = 0; kt < 4; ++kt) {
#pragma unroll
    for (int cc = 0; cc < 4; ++cc) {
      const int rr  = cc * 32 + sr;
      const int ksl = sl ^ (rr & 7);
      GLOAD_LDS16(bf + (size_t)(i0 + rr) * kD + kt * 64 + ksl * 8, Abuf + rr * 64 + sl * 8);
      GLOAD_LDS16(bf + (size_t)(j0 + rr) * kD + kt * 64 + ksl * 8, Bbuf + rr * 64 + sl * 8);
    }
    __syncthreads();
#pragma unroll
    for (int k32 = 0; k32 < 2; ++k32) {
      bf16x8 a[4], bv[4];
#pragma unroll
      for (int mi = 0; mi < 4; ++mi) {
        const int ra   = wm * 64 + mi * 16 + llo;
        const int slot = (k32 * 4 + lhi) ^ (ra & 7);
        a[mi] = *(const bf16x8*)(Abuf + ra * 64 + slot * 8);
      }
#pragma unroll
      for (int ni = 0; ni < 4; ++ni) {
        const int rb   = wn * 64 + ni * 16 + llo;
        const int slot = (k32 * 4 + lhi) ^ (rb & 7);
        bv[ni] = *(const bf16x8*)(Bbuf + rb * 64 + slot * 8);
      }
      __builtin_amdgcn_s_setprio(1);
#pragma unroll
      for (int mi = 0; mi < 4; ++mi)
#pragma unroll
        for (int ni = 0; ni < 4; ++ni)
          acc[mi][ni] = __builtin_amdgcn_mfma_f32_16x16x32_bf16(
              a[mi], bv[ni], acc[mi][ni], 0, 0, 0);
      __builtin_amdgcn_s_setprio(0);
    }
    __syncthreads();
  }

  float sqi_s[4][4], idi[4][4];
#pragma unroll
  for (int mi = 0; mi < 4; ++mi)
#pragma unroll
    for (int rr = 0; rr < 4; ++rr) {
      const float2 p = sqid[i0 + wm * 64 + mi * 16 + lhi * 4 + rr];
      sqi_s[mi][rr] = p.x * kInvD;
      idi[mi][rr]   = p.y;
    }
  float sqjm1[4], idj[4];
#pragma unroll
  for (int ni = 0; ni < 4; ++ni) {
    const float2 p = sqid[j0 + wn * 64 + ni * 16 + llo];
    sqjm1[ni] = p.x * kInvD - 1.0f;
    idj[ni]   = p.y;
  }

  float rowacc[4][4] = {};
  float colacc[4] = {};
#pragma unroll
  for (int mi = 0; mi < 4; ++mi)
#pragma unroll
    for (int ni = 0; ni < 4; ++ni)
#pragma unroll
      for (int rr = 0; rr < 4; ++rr) {
        float s1 = fmaf(acc[mi][ni][rr], -kInv2D, sqi_s[mi][rr] + sqjm1[ni]);
        s1 += (idi[mi][rr] == idj[ni]) ? 1.0f : 0.0f;
        const float tt = s1 * s1;
        rowacc[mi][rr] += tt;
        colacc[ni] += tt;
      }

#pragma unroll
  for (int mi = 0; mi < 4; ++mi)
#pragma unroll
    for (int rr = 0; rr < 4; ++rr) {
      float v = rowacc[mi][rr];
      v += __shfl_xor(v, 1);
      v += __shfl_xor(v, 2);
      v += __shfl_xor(v, 4);
      v += __shfl_xor(v, 8);
      if (llo == 0)
        atomicAdd(&out[i0 + wm * 64 + mi * 16 + lhi * 4 + rr], v * kInvN);
    }
#pragma unroll
  for (int ni = 0; ni < 4; ++ni) {
    float v = colacc[ni];
    v += __shfl_xor(v, 16);
    v += __shfl_xor(v, 32);
    if (lhi == 0)
      atomicAdd(&out[j0 + wn * 64 + ni * 16 + llo], v * kInvN);
  }
}

// ---------------------------------------------------------------------------
extern "C" void kernel_launch(void* const* d_in, const int* in_sizes, int n_in,
                              void* d_out, int out_size, void* d_ws, size_t ws_size,
                              hipStream_t stream) {
  const float* samples = (const float*)d_in[0];
  const float* input1  = (const float*)d_in[1];
  float* out = (float*)d_out;

  char* ws = (char*)d_ws;
  u16*    bf   = (u16*)ws;                                  // 4 MB bf16 samples
  float2* sqid = (float2*)(ws + (size_t)4 * 1024 * 1024);   // 64 KB {sq, id}

  // 128 KB dynamic LDS (mechanism proven in R5/R13)
  hipFuncSetAttribute(reinterpret_cast<const void*>(&simloss_main),
                      hipFuncAttributeMaxDynamicSharedMemorySize, 131072);

  prep_kernel<<<kN / 4, 256, 0, stream>>>(samples, input1, bf, sqid, out);
  simloss_main<<<dim3(64, 4), 256, 131072, stream>>>(bf, sqid, out);
  simloss_d32<<<32, 256, 0, stream>>>(bf, sqid, out);
}